// Round 5
// baseline (92.012 us; speedup 1.0000x reference)
//
#include <hip/hip_runtime.h>
#include <hip/hip_bf16.h>
#include <stdint.h>

#define N_W 96
#define N_F 96
#define NAG 192                      // total agents
#define NP1 97
#define W_ELEMS (N_W * NP1 * NP1)    // 903264 (divisible by 4)
#define R_ELEMS (NAG * NAG)          // 36864
#define WB ((W_ELEMS / 4 + 255) / 256)   // 883
#define RB ((R_ELEMS / 4 + 255) / 256)   // 36

// Decode one-hot tensors into packed index form.
// packed word [a*64 + s] = pref[a][s] | (pref[a][s+64] << 16)  (high half valid for s<33)
// ord[r] = dictating agent in round r (0..95 worker, 96..191 firm).
__global__ __launch_bounds__(256) void decode_kernel(
    const float* __restrict__ W, const float* __restrict__ F,
    const float* __restrict__ R,
    short* __restrict__ ps, short* __restrict__ ord) {
    int b = blockIdx.x;
    if (b < 2 * WB) {
        const float* src = (b < WB) ? W : F;
        int abase = (b < WB) ? 0 : N_W;
        int i4 = (b - ((b < WB) ? 0 : WB)) * 256 + threadIdx.x;
        if (i4 < W_ELEMS / 4) {
            float4 v = ((const float4*)src)[i4];
            int base = i4 * 4;
            #pragma unroll
            for (int u = 0; u < 4; ++u) {
                float x = (u == 0) ? v.x : (u == 1) ? v.y : (u == 2) ? v.z : v.w;
                if (x > 0.5f) {
                    int idx = base + u;
                    int a = idx / (NP1 * NP1);
                    int rem = idx - a * (NP1 * NP1);
                    int j = rem / NP1;          // option (firm/worker or 96=unmatch)
                    int k = rem - j * NP1;      // rank
                    int slot = (k < 64) ? (2 * k) : (2 * (k - 64) + 1);
                    ps[(abase + a) * 128 + slot] = (short)j;
                }
            }
        }
    } else {
        int i4 = (b - 2 * WB) * 256 + threadIdx.x;
        if (i4 < R_ELEMS / 4) {
            float4 v = ((const float4*)R)[i4];
            int base = i4 * 4;
            #pragma unroll
            for (int u = 0; u < 4; ++u) {
                float x = (u == 0) ? v.x : (u == 1) ? v.y : (u == 2) ? v.z : v.w;
                if (x > 0.5f) {
                    int idx = base + u;
                    int a = idx / NAG;
                    int r = idx - a * NAG;
                    ord[r] = (short)a;
                }
            }
        }
    }
}

// Single-block sequential serial dictatorship.
// ord in VGPRs (readlane), prefs ds_read depth-4 pipeline, masks in wave-uniform
// u64 (SGPR), branchless round body, all-lane uniform s_match writes.
__global__ __launch_bounds__(256, 1) void sd_kernel(
    const uint32_t* __restrict__ pk_g, const short* __restrict__ ord_g,
    float* __restrict__ out) {
    __shared__ __align__(16) uint32_t s_pk[NAG * 64];   // 48 KiB packed prefs
    __shared__ uint32_t s_match[NAG];                   // matched cell per round, ~0 = none

    const int t = threadIdx.x;
    for (int i = t; i < NAG * 16; i += 256)
        ((uint4*)s_pk)[i] = ((const uint4*)pk_g)[i];
    __syncthreads();

    if (t < 64) {
        const unsigned short* ou = (const unsigned short*)ord_g;
        uint32_t ordv0 = ou[t], ordv1 = ou[64 + t], ordv2 = ou[128 + t];

        uint64_t rWlo = 0, rWhi = 0, rFlo = 0, rFhi = 0;   // removal masks (uniform)

        auto getA = [&](int r) -> int {
            int lane = r & 63;
            int v0 = __builtin_amdgcn_readlane((int)ordv0, lane);
            int v1 = __builtin_amdgcn_readlane((int)ordv1, lane);
            int v2 = __builtin_amdgcn_readlane((int)ordv2, lane);
            int seg = r >> 6;
            return (seg == 0) ? v0 : ((seg == 1) ? v1 : v2);
        };

        int A[4]; uint32_t P[4];
        uint64_t B1L[4], B1H[4], B2L[4], B2H[4];
        int An[4]; uint32_t Pn[4];

        auto DERIVE = [&](int i) {
            uint32_t p = P[i];
            uint32_t j1 = p & 0xFFFFu, j2 = p >> 16;
            uint64_t s1 = 1ull << (j1 & 63);
            uint64_t s2 = 1ull << (j2 & 63);
            B1L[i] = (j1 < 64) ? s1 : 0ull;
            B1H[i] = (j1 >= 64 && j1 < 96) ? s1 : 0ull;
            B2L[i] = (j2 < 64) ? s2 : 0ull;
            B2H[i] = (j2 >= 64 && j2 < 96) ? s2 : 0ull;
        };

        auto ROUND = [&](int r, int i) {
            int a = A[i];
            bool isW = a < 96;
            int aa = isW ? a : a - 96;
            int aab = aa & 63;
            bool alt = aa < 64;
            uint64_t sb = 1ull << aab;
            // dead check (own side, pre-update): chosen earlier <=> bit already set
            uint64_t ownw = isW ? (alt ? rWlo : rWhi) : (alt ? rFlo : rFhi);
            uint32_t dead = (uint32_t)(ownw >> aab) & 1u;
            // unconditional self-removal (own side; opposite side untouched)
            uint64_t sl = alt ? sb : 0ull, sh = alt ? 0ull : sb;
            rWlo |= isW ? sl : 0ull;  rWhi |= isW ? sh : 0ull;
            rFlo |= isW ? 0ull : sl;  rFhi |= isW ? 0ull : sh;
            // first available choice on the opposite side
            uint64_t olo = isW ? rFlo : rWlo;
            uint64_t ohi = isW ? rFhi : rWhi;
            uint64_t x1 = (olo & B1L[i]) | (ohi & B1H[i]);
            uint64_t x2 = (olo & B2L[i]) | (ohi & B2H[i]);
            unsigned long long m1 = __ballot(x1 == 0ull);
            unsigned long long m2 = __ballot(x2 == 0ull) & 0x1FFFFFFFFull;
            int k = (m1 != 0ull) ? (__ffsll(m1) - 1) : (64 + __ffsll(m2) - 1);
            uint32_t pc = (uint32_t)__builtin_amdgcn_readlane((int)P[i], k & 63);
            uint32_t js = (k & 64) ? (pc >> 16) : (pc & 0xFFFFu);
            // remove chosen counterpart from own-side availability (they're on opposite lists)
            uint64_t cb = 1ull << (js & 63);
            bool take = (js < 96) && (dead == 0u);
            uint64_t cl = (take && js < 64) ? cb : 0ull;
            uint64_t ch = (take && js >= 64) ? cb : 0ull;
            rFlo |= isW ? cl : 0ull;  rFhi |= isW ? ch : 0ull;
            rWlo |= isW ? 0ull : cl;  rWhi |= isW ? 0ull : ch;
            uint32_t cell = dead ? 0xFFFFFFFFu
                                 : (isW ? (uint32_t)(aa * NP1 + (int)js)
                                        : (uint32_t)((int)js * NP1 + aa));
            s_match[r] = cell;   // all lanes, same address+value: collapses, no branch
        };

        // prologue: prep iteration 0
        #pragma unroll
        for (int i = 0; i < 4; ++i) { A[i] = getA(i); P[i] = s_pk[(A[i] << 6) + t]; }
        #pragma unroll
        for (int i = 0; i < 4; ++i) DERIVE(i);

        for (int g = 0; g < 48; ++g) {
            int rb = g << 2;
            // issue next iteration's pref loads (addresses independent of masks)
            #pragma unroll
            for (int i = 0; i < 4; ++i) {
                An[i] = getA(rb + 4 + i);           // overruns past 191 read valid ord data
                Pn[i] = s_pk[(An[i] << 6) + t];
            }
            #pragma unroll
            for (int i = 0; i < 4; ++i) ROUND(rb + i, i);
            #pragma unroll
            for (int i = 0; i < 4; ++i) { A[i] = An[i]; P[i] = Pn[i]; }
            #pragma unroll
            for (int i = 0; i < 4; ++i) DERIVE(i);
        }
    } else {
        // waves 1-3: zero-fill output concurrently with wave 0's sequential loop
        for (int i = t - 64; i < 2352; i += 192)
            ((float4*)out)[i] = make_float4(0.f, 0.f, 0.f, 0.f);
        if (t == 64) out[9408] = 0.f;
    }
    __syncthreads();
    if (t < NAG) {
        uint32_t c = s_match[t];
        if (c != 0xFFFFFFFFu) out[c] = 1.0f;
    }
}

extern "C" void kernel_launch(void* const* d_in, const int* in_sizes, int n_in,
                              void* d_out, int out_size, void* d_ws, size_t ws_size,
                              hipStream_t stream) {
    const float* W = (const float*)d_in[0];
    const float* F = (const float*)d_in[1];
    const float* R = (const float*)d_in[2];
    float* out = (float*)d_out;

    uint32_t* packed = (uint32_t*)d_ws;                 // NAG*64 u32 = 48 KiB
    short* ord = (short*)((char*)d_ws + NAG * 64 * 4);  // 192 shorts

    decode_kernel<<<2 * WB + RB, 256, 0, stream>>>(W, F, R, (short*)packed, ord);
    sd_kernel<<<1, 256, 0, stream>>>(packed, ord, out);
}

// Round 6
// 49.421 us; speedup vs baseline: 1.8618x; 1.8618x over previous
//
#include <hip/hip_runtime.h>
#include <hip/hip_bf16.h>
#include <stdint.h>

#define N_W 96
#define N_F 96
#define NAG 192                      // total agents
#define NP1 97
#define W_ELEMS (N_W * NP1 * NP1)    // 903264 (divisible by 4)
#define R_ELEMS (NAG * NAG)          // 36864
#define WB ((W_ELEMS / 4 + 255) / 256)   // 883
#define RB ((R_ELEMS / 4 + 255) / 256)   // 36

// Decode one-hot tensors into packed index form.
// packed word [a*64 + s] = pref[a][s] | (pref[a][s+64] << 16)  (high half valid for s<33)
// ord[r] = dictating agent in round r (0..95 worker, 96..191 firm).
__global__ __launch_bounds__(256) void decode_kernel(
    const float* __restrict__ W, const float* __restrict__ F,
    const float* __restrict__ R,
    short* __restrict__ ps, short* __restrict__ ord) {
    int b = blockIdx.x;
    if (b < 2 * WB) {
        const float* src = (b < WB) ? W : F;
        int abase = (b < WB) ? 0 : N_W;
        int i4 = (b - ((b < WB) ? 0 : WB)) * 256 + threadIdx.x;
        if (i4 < W_ELEMS / 4) {
            float4 v = ((const float4*)src)[i4];
            int base = i4 * 4;
            #pragma unroll
            for (int u = 0; u < 4; ++u) {
                float x = (u == 0) ? v.x : (u == 1) ? v.y : (u == 2) ? v.z : v.w;
                if (x > 0.5f) {
                    int idx = base + u;
                    int a = idx / (NP1 * NP1);
                    int rem = idx - a * (NP1 * NP1);
                    int j = rem / NP1;          // option (firm/worker or 96=unmatch)
                    int k = rem - j * NP1;      // rank
                    int slot = (k < 64) ? (2 * k) : (2 * (k - 64) + 1);
                    ps[(abase + a) * 128 + slot] = (short)j;
                }
            }
        }
    } else {
        int i4 = (b - 2 * WB) * 256 + threadIdx.x;
        if (i4 < R_ELEMS / 4) {
            float4 v = ((const float4*)R)[i4];
            int base = i4 * 4;
            #pragma unroll
            for (int u = 0; u < 4; ++u) {
                float x = (u == 0) ? v.x : (u == 1) ? v.y : (u == 2) ? v.z : v.w;
                if (x > 0.5f) {
                    int idx = base + u;
                    int a = idx / NAG;
                    int r = idx - a * NAG;
                    ord[r] = (short)a;
                }
            }
        }
    }
}

#define LOAD8(dst, rb) \
    dst##0 = s_pko[((rb) << 6) + t];        \
    dst##1 = s_pko[((rb) << 6) + 64 + t];   \
    dst##2 = s_pko[((rb) << 6) + 128 + t];  \
    dst##3 = s_pko[((rb) << 6) + 192 + t];  \
    dst##4 = s_pko[((rb) << 6) + 256 + t];  \
    dst##5 = s_pko[((rb) << 6) + 320 + t];  \
    dst##6 = s_pko[((rb) << 6) + 384 + t];  \
    dst##7 = s_pko[((rb) << 6) + 448 + t];

#define GROUP8(rb, P_) do {                                                 \
    int seg_ = (rb) >> 6;                                                   \
    uint32_t osel_ = (seg_ == 0) ? ordv0 : (seg_ == 1) ? ordv1 : ordv2;     \
    ROUND((rb) + 0, P_##0, osel_);                                          \
    ROUND((rb) + 1, P_##1, osel_);                                          \
    ROUND((rb) + 2, P_##2, osel_);                                          \
    ROUND((rb) + 3, P_##3, osel_);                                          \
    ROUND((rb) + 4, P_##4, osel_);                                          \
    ROUND((rb) + 5, P_##5, osel_);                                          \
    ROUND((rb) + 6, P_##6, osel_);                                          \
    ROUND((rb) + 7, P_##7, osel_);                                          \
} while (0)

// MODE 1 = real kernel; MODE 0 = staging-only diagnostic (out points into d_ws)
template <int MODE>
__global__ __launch_bounds__(256, 1) void sd_kernel(
    const uint32_t* __restrict__ pk_g, const short* __restrict__ ord_g,
    float* __restrict__ out) {
    __shared__ __align__(16) uint32_t s_pko[NAG * 64];   // 48 KiB, round-ordered prefs
    __shared__ uint32_t s_match[NAG];

    const int t = threadIdx.x;
    const unsigned short* og = (const unsigned short*)ord_g;

    // staging: s_pko[r][lane] = pk[ord[r]][lane]  (indirection paid here, in parallel)
    for (int idx = t; idx < NAG * 16; idx += 256) {
        int r = idx >> 4, q = idx & 15;
        int a = (int)og[r];
        ((uint4*)s_pko)[idx] = ((const uint4*)(pk_g + (a << 6)))[q];
    }
    if (t < NAG) s_match[t] = 0xFFFFFFFFu;
    __syncthreads();

    if (MODE == 0) {
        // diagnostic: fill out (ws area) from s_pko so staging isn't DCE'd
        for (int i = t; i < 2352; i += 256)
            ((float4*)out)[i] = ((float4*)s_pko)[i];
        if (t == 0) out[9408] = 0.f;
    } else if (t < 64) {
        uint32_t ordv0 = og[t], ordv1 = og[64 + t], ordv2 = og[128 + t];
        uint64_t rWlo = 0, rWhi = 0, rFlo = 0, rFhi = 0;   // removal masks (uniform -> SGPR)

        auto ROUND = [&](int r, uint32_t P, uint32_t osel) {
            // per-lane derive (independent of masks)
            uint32_t j1 = P & 0xFFFFu, j2 = P >> 16;
            uint32_t s1 = j1 & 63u, s2 = j2 & 63u;
            uint32_t lo1 = (j1 < 64u) ? 1u : 0u;
            uint32_t hi1 = (j1 >= 64u && j1 < 96u) ? 1u : 0u;
            uint32_t lo2 = (j2 < 64u) ? 1u : 0u;
            uint32_t hi2 = (j2 >= 64u && j2 < 96u) ? 1u : 0u;
            int a = __builtin_amdgcn_readlane((int)osel, r & 63);   // uniform
            if (a < 96) {            // worker dictates
                uint64_t own = (a < 64) ? rWlo : rWhi;
                bool dead = ((own >> (a & 63)) & 1ull) != 0ull;
                uint64_t sb = 1ull << (a & 63);
                if (a < 64) rWlo |= sb; else rWhi |= sb;     // self-removal
                if (!dead) {
                    uint32_t bad1 = (((uint32_t)(rFlo >> s1)) & lo1)
                                  | (((uint32_t)(rFhi >> s1)) & hi1);
                    uint32_t bad2 = (((uint32_t)(rFlo >> s2)) & lo2)
                                  | (((uint32_t)(rFhi >> s2)) & hi2);
                    unsigned long long m1 = __ballot(bad1 == 0u);
                    unsigned long long m2 = __ballot(bad2 == 0u);
                    int k = (m1 != 0ull) ? (__ffsll(m1) - 1) : (63 + __ffsll(m2));
                    uint32_t pc = (uint32_t)__builtin_amdgcn_readlane((int)P, k & 63);
                    uint32_t js = (k >= 64) ? (pc >> 16) : (pc & 0xFFFFu);
                    s_match[r] = (uint32_t)(a * NP1 + (int)js);   // uniform all-lane write
                    if (js < 96u) {
                        uint64_t cb = 1ull << (js & 63u);
                        if (js < 64u) rFlo |= cb; else rFhi |= cb;
                    }
                }
            } else {                 // firm dictates
                int aa = a - 96;
                uint64_t own = (aa < 64) ? rFlo : rFhi;
                bool dead = ((own >> (aa & 63)) & 1ull) != 0ull;
                uint64_t sb = 1ull << (aa & 63);
                if (aa < 64) rFlo |= sb; else rFhi |= sb;
                if (!dead) {
                    uint32_t bad1 = (((uint32_t)(rWlo >> s1)) & lo1)
                                  | (((uint32_t)(rWhi >> s1)) & hi1);
                    uint32_t bad2 = (((uint32_t)(rWlo >> s2)) & lo2)
                                  | (((uint32_t)(rWhi >> s2)) & hi2);
                    unsigned long long m1 = __ballot(bad1 == 0u);
                    unsigned long long m2 = __ballot(bad2 == 0u);
                    int k = (m1 != 0ull) ? (__ffsll(m1) - 1) : (63 + __ffsll(m2));
                    uint32_t pc = (uint32_t)__builtin_amdgcn_readlane((int)P, k & 63);
                    uint32_t js = (k >= 64) ? (pc >> 16) : (pc & 0xFFFFu);
                    s_match[r] = (uint32_t)((int)js * NP1 + aa);
                    if (js < 96u) {
                        uint64_t cb = 1ull << (js & 63u);
                        if (js < 64u) rWlo |= cb; else rWhi |= cb;
                    }
                }
            }
        };

        uint32_t Pa0, Pa1, Pa2, Pa3, Pa4, Pa5, Pa6, Pa7;
        uint32_t Pb0, Pb1, Pb2, Pb3, Pb4, Pb5, Pb6, Pb7;
        LOAD8(Pa, 0);
        for (int g = 0; g < 24; g += 2) {
            int rb1 = (g + 1) << 3;
            LOAD8(Pb, rb1);                          // prefetch next group
            GROUP8(g << 3, Pa);
            int g2 = g + 2;
            int rb2 = ((g2 < 24) ? g2 : 23) << 3;    // clamp: harmless reload at the end
            LOAD8(Pa, rb2);
            GROUP8(rb1, Pb);
        }
    } else {
        // waves 1-3: zero-fill output concurrently with wave 0's loop
        for (int i = t - 64; i < 2352; i += 192)
            ((float4*)out)[i] = make_float4(0.f, 0.f, 0.f, 0.f);
        if (t == 64) out[9408] = 0.f;
    }
    __syncthreads();
    if (t < NAG) {
        uint32_t c = s_match[t];
        if (c != 0xFFFFFFFFu) out[c] = 1.0f;
    }
}

extern "C" void kernel_launch(void* const* d_in, const int* in_sizes, int n_in,
                              void* d_out, int out_size, void* d_ws, size_t ws_size,
                              hipStream_t stream) {
    const float* W = (const float*)d_in[0];
    const float* F = (const float*)d_in[1];
    const float* R = (const float*)d_in[2];
    float* out = (float*)d_out;

    uint32_t* packed = (uint32_t*)d_ws;                 // NAG*64 u32 = 48 KiB
    short* ord = (short*)((char*)d_ws + NAG * 64 * 4);  // 192 shorts
    float* diag = (float*)((char*)d_ws + (64 << 10));   // diagnostic dump area

    decode_kernel<<<2 * WB + RB, 256, 0, stream>>>(W, F, R, (short*)packed, ord);
    if (ws_size >= (128u << 10))
        sd_kernel<0><<<1, 256, 0, stream>>>(packed, ord, diag);   // staging-cost probe
    sd_kernel<1><<<1, 256, 0, stream>>>(packed, ord, out);
}